// Round 6
// baseline (3136.455 us; speedup 1.0000x reference)
//
#include <hip/hip_runtime.h>

// ResidualVectorQuantizer: N=131072, DIM=128, LEVELS=3, K=1024, BETA=0.25, USAGE_REG=1e-3
// Outputs (flat fp32 in d_out): quantized [N*128] | codes [N*3] | commit | usage
//
// Numerics contract with the np fp32 reference (validated previously — do not change):
//  - m = x·W_k: strict sequential fmaf chain over k=0..127, single accumulator.
//  - d = (S - 2*m) + w via __fsub_rn/__fmul_rn/__fadd_rn (no contraction).
//  - argmin: first occurrence on ties (lexicographic (value, index) min).
//  - residual chain (x - q0) - q1 elementwise fp32, recomputed from codes per level.
//  - Srow: per-8-elem left-assoc square sums, then 16-chunk ascending sum.
//  - losses: tolerance loose (~2%); commit = sum of d at argmin; avgp fp32; KL f64.
//
// Round 11. Five structurally different kernels (2-wave/92reg, 8-wave/60reg,
// 64reg+spill, 68reg clean pipeline) ALL land at 955-1045 us/level -> the
// bottleneck is what they share: rows broadcast from LDS (ds_read+lgkm waits
// inside the FMA stream), VGPR-addressed W loads (VALU bumps), thin residency.
// Fix: rows are WAVE-UNIFORM -> move them to the scalar pipe. A per-level
// stage_level kernel writes residuals k-major (resT[k][n], scratch = the
// output's quantized region, 64MB, only written by the final gather) + Srow.
// rvq_level then has NO phase 0, NO row LDS: rows arrive via s_load_dwordx8
// (SMEM pipe -> SGPRs), W via uniform-base+const-voffset (SALU bumps), and the
// hot loop is pure v_fmac v_acc, s_row, v_w. Live VGPRs ~62 (< the 64 tier the
// allocator always targets) -> no war, 7-8 waves/SIMD TLP + W ping-pong.
// All fp32 values and rounding orders are unchanged (data relocated only).
// Checks: rvq SGPR must jump to ~80-100 (s_loads), VGPR ~64, LDS ~1.3KB,
// WRITE ~133MB. If SGPR stays 48 -> compiler refused scalar loads, rethink.

#define NROWS   131072
#define DIMS    128
#define KCODES  1024
#define NLEV    3

#define QF_OFF   ((size_t)NROWS * DIMS)          // 16777216
#define CODE_OFF QF_OFF
#define SCAL_OFF (QF_OFF + (size_t)NROWS * 3)    // 17170432

// ---------------- ws layout ----------------
// avgp   : 3*1024 floats  @ 0        (12288 B)
// commit : 3 doubles      @ 12288    (24 B)
// wk     : 3*1024 floats  @ 12320    (12288 B)
// WT2    : 3*128*1024 fl  @ 24608    (1572864 B)  k-pair-interleaved codebooks
// SrowG  : 131072 floats  @ 1597472  (524288 B)   per-level ||residual row||^2
#define WS_COMMIT_OFF 12288
#define WS_WK_OFF     12320
#define WS_WT_OFF     24608
#define WS_SROW_OFF   1597472

__global__ __launch_bounds__(256) void init_acc(float* avgp, double* commit) {
    for (int i = threadIdx.x; i < 3072; i += 256) avgp[i] = 0.0f;
    if (threadIdx.x < 3) commit[threadIdx.x] = 0.0;
}

__global__ __launch_bounds__(256) void wnorm_kernel(const float* __restrict__ W,
                                                    float* __restrict__ wk) {
    const int wave = threadIdx.x >> 6, lane = threadIdx.x & 63;
    const int c = blockIdx.x * 4 + wave;          // 0..3071 (level*1024 + k)
    const float2 v = *(const float2*)(W + (size_t)c * DIMS + 2 * lane);
    float s = v.x * v.x + v.y * v.y;
#pragma unroll
    for (int m = 32; m >= 1; m >>= 1) s += __shfl_xor(s, m, 64);
    if (lane == 0) wk[c] = s;
}

// WT2[l][(k>>1)*2048 + c*2 + (k&1)] = W[l][c][k]  (k-pair interleaved)
__global__ __launch_bounds__(256) void transpose_w(const float* __restrict__ W,
                                                   float* __restrict__ WT2) {
    __shared__ float tile[32][65];
    const int l = blockIdx.z, k0 = blockIdx.y * 32, c0 = blockIdx.x * 64;
    const float* Wl = W + (size_t)l * KCODES * DIMS;
    float* W2l = WT2 + (size_t)l * DIMS * KCODES;
    {
        const int ci = threadIdx.x >> 2;            // 0..63
        const int kg = (threadIdx.x & 3) * 8;       // 0,8,16,24
        const float4 a = *(const float4*)(Wl + (size_t)(c0 + ci) * DIMS + k0 + kg);
        const float4 b = *(const float4*)(Wl + (size_t)(c0 + ci) * DIMS + k0 + kg + 4);
        tile[kg + 0][ci] = a.x; tile[kg + 1][ci] = a.y;
        tile[kg + 2][ci] = a.z; tile[kg + 3][ci] = a.w;
        tile[kg + 4][ci] = b.x; tile[kg + 5][ci] = b.y;
        tile[kg + 6][ci] = b.z; tile[kg + 7][ci] = b.w;
    }
    __syncthreads();
    {
        const int kp = threadIdx.x >> 4;            // 0..15 (k-pair within tile)
        const int cl = (threadIdx.x & 15) * 4;      // 0..60 (4 codes per thread)
        float4 o0, o1;                               // (c,k0),(c,k1),(c+1,k0),(c+1,k1)
        o0.x = tile[2 * kp][cl + 0]; o0.y = tile[2 * kp + 1][cl + 0];
        o0.z = tile[2 * kp][cl + 1]; o0.w = tile[2 * kp + 1][cl + 1];
        o1.x = tile[2 * kp][cl + 2]; o1.y = tile[2 * kp + 1][cl + 2];
        o1.z = tile[2 * kp][cl + 3]; o1.w = tile[2 * kp + 1][cl + 3];
        const size_t k2g = (size_t)(k0 >> 1) + kp;
        float* dst = W2l + (k2g * KCODES + (c0 + cl)) * 2;
        *(float4*)(dst)     = o0;
        *(float4*)(dst + 4) = o1;
    }
}

// stage_level: residual rows for `level`, written k-major (resT[k][n]) + Srow.
// Residual chain and Srow chunk sums are bit-identical to the old phase 0
// (same __fsub_rn order per element, same 8-elem left-assoc square chains,
// same 16-chunk ascending Srow sum) — only distributed differently.
__global__ __launch_bounds__(256) void stage_level(
    const float* __restrict__ x, const float* __restrict__ W,
    const float* __restrict__ codesF, float* __restrict__ resT,
    float* __restrict__ SrowG, const int level) {

    __shared__ float tileT[128][68];   // [k][r], padded (16B-aligned rows)
    __shared__ float redf[64][17];
    const int t = threadIdx.x;
    const int r = t >> 2, iq = t & 3;               // 64 rows x 4 quarters
    const size_t n = (size_t)blockIdx.x * 64 + r;

    float4 v[8];
#pragma unroll
    for (int j = 0; j < 8; ++j)
        v[j] = *(const float4*)(x + n * DIMS + iq * 32 + j * 4);
    for (int l = 0; l < level; ++l) {
        const int idx = (int)codesF[n * 3 + l];
        const float* q = W + ((size_t)(l * KCODES + idx)) * DIMS + iq * 32;
#pragma unroll
        for (int j = 0; j < 8; ++j) {
            const float4 qv = *(const float4*)(q + j * 4);
            v[j].x = __fsub_rn(v[j].x, qv.x);
            v[j].y = __fsub_rn(v[j].y, qv.y);
            v[j].z = __fsub_rn(v[j].z, qv.z);
            v[j].w = __fsub_rn(v[j].w, qv.w);
        }
    }
#pragma unroll
    for (int j = 0; j < 8; ++j) {
        const int k = iq * 32 + j * 4;
        tileT[k + 0][r] = v[j].x; tileT[k + 1][r] = v[j].y;
        tileT[k + 2][r] = v[j].z; tileT[k + 3][r] = v[j].w;
    }
#pragma unroll
    for (int jj = 0; jj < 4; ++jj) {    // chunk index = iq*4+jj, elems *8..*8+7
        const float4 a = v[2 * jj], b = v[2 * jj + 1];
        float sq = a.x * a.x + a.y * a.y + a.z * a.z + a.w * a.w
                 + b.x * b.x + b.y * b.y + b.z * b.z + b.w * b.w;
        redf[r][iq * 4 + jj] = sq;
    }
    __syncthreads();
    if (t < 64) {
        float s = 0.f;
        for (int i = 0; i < 16; ++i) s += redf[t][i];
        SrowG[(size_t)blockIdx.x * 64 + t] = s;
    }
    {
        const int k = t >> 1, half = t & 1;         // 128 k-rows x 2 halves
        float* dst = resT + (size_t)k * NROWS + (size_t)blockIdx.x * 64 + half * 32;
#pragma unroll
        for (int j = 0; j < 8; ++j)
            *(float4*)(dst + 4 * j) = *(const float4*)&tileT[k][half * 32 + 4 * j];
    }
}

// 2-k step for 4 codes; rs operands are wave-uniform (SGPR). Per accumulator:
// fmaf(k0) then fmaf(k1) — the same single ascending-k chain as always.
#define FMA8(A, r0v, r1v, u, v)                                                \
    A.x = fmaf(r1v, u.y, fmaf(r0v, u.x, A.x));                                 \
    A.y = fmaf(r1v, u.w, fmaf(r0v, u.z, A.y));                                 \
    A.z = fmaf(r1v, v.y, fmaf(r0v, v.x, A.z));                                 \
    A.w = fmaf(r1v, v.w, fmaf(r0v, v.z, A.w));

__global__ __launch_bounds__(256) void rvq_level(
    const float* __restrict__ resT, const float* __restrict__ SrowG,
    const float* __restrict__ WT2, const float* __restrict__ wk,
    float* __restrict__ out, float* __restrict__ avgp,
    double* __restrict__ commit, const int level) {

    __shared__ float wminv[16][4];    // per-wave (row) argmin partials
    __shared__ int   wmini[16][4];
    __shared__ float rowmin[16];
    __shared__ float wsum[16][4];
    __shared__ float rcpL[16];

    const int t = threadIdx.x;
    const int wave = t >> 6, lane = t & 63;
    const int c = wave * 256 + lane * 4;          // this thread's 4 codes
    const int c2 = 2 * c;                         // float offset into k-pair rows
    const size_t base = (size_t)blockIdx.x * 16;
    const float* W2l = WT2 + (size_t)level * DIMS * KCODES;
    const float* wkl = wk + level * KCODES;
    const float4 wkv = *(const float4*)(wkl + c);
    float s0 = 0.f, s1 = 0.f, s2 = 0.f, s3 = 0.f;   // phase-4 partials

#pragma unroll 1
    for (int rg = 0; rg < 2; ++rg) {
        const int r0 = rg * 8;
        const size_t rowbase = base + r0;

        float4 acc[8];
#pragma unroll
        for (int r = 0; r < 8; ++r) { acc[r].x = 0.f; acc[r].y = 0.f; acc[r].z = 0.f; acc[r].w = 0.f; }

        // prologue: W k-pair 0 into bufA (uniform base + constant thread offset)
        float4 a0 = *(const float4*)(W2l + c2);
        float4 a1 = *(const float4*)(W2l + c2 + 4);

#pragma unroll 1
        for (int kp = 0; kp < 64; kp += 2) {
            // prefetch W k-pair kp+1 into bufB
            const float* pB = W2l + (size_t)(kp + 1) * 2048;
            const float4 b0 = *(const float4*)(pB + c2);
            const float4 b1 = *(const float4*)(pB + c2 + 4);
            // rows k = 2kp, 2kp+1 (uniform -> scalar loads into SGPRs)
            const float* rp = resT + (size_t)(2 * kp) * NROWS + rowbase;
            float ra0[8], ra1[8];
#pragma unroll
            for (int r = 0; r < 8; ++r) ra0[r] = rp[r];
#pragma unroll
            for (int r = 0; r < 8; ++r) ra1[r] = rp[NROWS + r];
#pragma unroll
            for (int r = 0; r < 8; ++r) { FMA8(acc[r], ra0[r], ra1[r], a0, a1); }

            // prefetch W k-pair kp+2 into bufA (clamped, dead on last iter)
            const float* pA = (kp + 2 < 64) ? (W2l + (size_t)(kp + 2) * 2048) : W2l;
            a0 = *(const float4*)(pA + c2);
            a1 = *(const float4*)(pA + c2 + 4);
            // rows k = 2kp+2, 2kp+3
            const float* rq = resT + (size_t)(2 * kp + 2) * NROWS + rowbase;
            float rb0[8], rb1[8];
#pragma unroll
            for (int r = 0; r < 8; ++r) rb0[r] = rq[r];
#pragma unroll
            for (int r = 0; r < 8; ++r) rb1[r] = rq[NROWS + r];
#pragma unroll
            for (int r = 0; r < 8; ++r) { FMA8(acc[r], rb0[r], rb1[r], b0, b1); }
        }

        // ---- phase 2: d in place, per-row argmin (lexicographic shuffle reduce) ----
#pragma unroll
        for (int r = 0; r < 8; ++r) {
            const float Sr = SrowG[rowbase + r];    // uniform scalar load
            float4 A = acc[r];
            A.x = __fadd_rn(__fsub_rn(Sr, __fmul_rn(2.0f, A.x)), wkv.x);
            A.y = __fadd_rn(__fsub_rn(Sr, __fmul_rn(2.0f, A.y)), wkv.y);
            A.z = __fadd_rn(__fsub_rn(Sr, __fmul_rn(2.0f, A.z)), wkv.z);
            A.w = __fadd_rn(__fsub_rn(Sr, __fmul_rn(2.0f, A.w)), wkv.w);
            acc[r] = A;
            float v = A.x; int bi = c;
            if (A.y < v) { v = A.y; bi = c + 1; }
            if (A.z < v) { v = A.z; bi = c + 2; }
            if (A.w < v) { v = A.w; bi = c + 3; }
#pragma unroll
            for (int m = 1; m < 64; m <<= 1) {
                const float vo = __shfl_xor(v, m, 64);
                const int   io = __shfl_xor(bi, m, 64);
                if (vo < v || (vo == v && io < bi)) { v = vo; bi = io; }
            }
            if (lane == 0) { wminv[r0 + r][wave] = v; wmini[r0 + r][wave] = bi; }
        }
        __syncthreads();
        if (t < 8) {
            float v = wminv[r0 + t][0]; int bi = wmini[r0 + t][0];
            for (int w = 1; w < 4; ++w) {
                const float vo = wminv[r0 + t][w]; const int io = wmini[r0 + t][w];
                if (vo < v || (vo == v && io < bi)) { v = vo; bi = io; }
            }
            rowmin[r0 + t] = v;
            out[CODE_OFF + (base + r0 + t) * 3 + level] = (float)bi;
        }
        __syncthreads();

        // ---- phase 3: e = exp(dmin - d) in place, row sums via shuffle ----
#pragma unroll
        for (int r = 0; r < 8; ++r) {
            const float mn = rowmin[r0 + r];
            float4 A = acc[r];
            A.x = expf(__fsub_rn(mn, A.x));
            A.y = expf(__fsub_rn(mn, A.y));
            A.z = expf(__fsub_rn(mn, A.z));
            A.w = expf(__fsub_rn(mn, A.w));
            acc[r] = A;
            float s = (A.x + A.y) + (A.z + A.w);
#pragma unroll
            for (int m = 1; m < 64; m <<= 1) s += __shfl_xor(s, m, 64);
            if (lane == 0) wsum[r0 + r][wave] = s;
        }
        __syncthreads();
        if (t < 8) {
            const float L = (wsum[r0 + t][0] + wsum[r0 + t][1])
                          + (wsum[r0 + t][2] + wsum[r0 + t][3]);
            rcpL[r0 + t] = 1.0f / L;
        }
        __syncthreads();

        // ---- phase 4 partial: accumulate avg_probs contributions in registers ----
#pragma unroll
        for (int r = 0; r < 8; ++r) {
            const float rl = rcpL[r0 + r];
            s0 = fmaf(acc[r].x, rl, s0);
            s1 = fmaf(acc[r].y, rl, s1);
            s2 = fmaf(acc[r].z, rl, s2);
            s3 = fmaf(acc[r].w, rl, s3);
        }
    }

    // ---- commit partial: d at argmin == ||r - q||^2 (loss tolerance loose) ----
    if (t == 64) {
        double cs = 0.0;
        for (int r = 0; r < 16; ++r) cs += (double)rowmin[r];
        atomicAdd(&commit[level], cs);
    }

    // ---- avg_probs atomics: one per code per block ----
    atomicAdd(&avgp[level * KCODES + c + 0], s0);
    atomicAdd(&avgp[level * KCODES + c + 1], s1);
    atomicAdd(&avgp[level * KCODES + c + 2], s2);
    atomicAdd(&avgp[level * KCODES + c + 3], s3);
}

__global__ __launch_bounds__(256) void finalize_kernel(const float* __restrict__ avgp,
                                                       const double* __restrict__ commit,
                                                       float* __restrict__ out) {
    __shared__ double red[256];
    __shared__ float  kls[3];
    const int t = threadIdx.x;
    for (int l = 0; l < 3; ++l) {
        double p = 0.0;
        for (int k = t; k < KCODES; k += 256) {
            const float avg = avgp[l * KCODES + k] * (1.0f / 131072.0f);
            p += (double)avg * log((double)avg * 1024.0 + 1e-8);
        }
        red[t] = p; __syncthreads();
        for (int off = 128; off >= 1; off >>= 1) {
            if (t < off) red[t] += red[t + off];
            __syncthreads();
        }
        if (t == 0) kls[l] = (float)red[0];
        __syncthreads();
    }
    if (t == 0) {
        float cv = 0.f, u = 0.f;
        for (int l = 0; l < 3; ++l) {
            const float m = (float)(commit[l] * (1.0 / 16777216.0));
            cv = __fadd_rn(cv, m);                      // + mean((sg(r)-q)^2)
            cv = __fadd_rn(cv, __fmul_rn(0.25f, m));    // + BETA * mean((r-sg(q))^2)
            u = __fadd_rn(u, __fmul_rn(1e-3f, kls[l]));
        }
        out[SCAL_OFF]     = cv;
        out[SCAL_OFF + 1] = u;
    }
}

__global__ __launch_bounds__(256) void gather_kernel(const float* __restrict__ W,
                                                     float* __restrict__ out) {
    const size_t g = (size_t)blockIdx.x * 256 + threadIdx.x;   // f4 index
    const size_t n = g >> 5;
    const int f = (int)(g & 31);
    const float* codes = out + CODE_OFF + n * 3;
    const int c0 = (int)codes[0], c1 = (int)codes[1], c2 = (int)codes[2];
    const float4 a = *(const float4*)(W + (size_t)c0 * DIMS + 4 * f);
    const float4 b = *(const float4*)(W + (size_t)(KCODES + c1) * DIMS + 4 * f);
    const float4 c = *(const float4*)(W + (size_t)(2 * KCODES + c2) * DIMS + 4 * f);
    float4 o;   // ((q1 + q2) + q3), fp32 like reference
    o.x = __fadd_rn(__fadd_rn(a.x, b.x), c.x);
    o.y = __fadd_rn(__fadd_rn(a.y, b.y), c.y);
    o.z = __fadd_rn(__fadd_rn(a.z, b.z), c.z);
    o.w = __fadd_rn(__fadd_rn(a.w, b.w), c.w);
    *(float4*)(out + n * DIMS + 4 * f) = o;
}

extern "C" void kernel_launch(void* const* d_in, const int* in_sizes, int n_in,
                              void* d_out, int out_size, void* d_ws, size_t ws_size,
                              hipStream_t stream) {
    const float* x = (const float*)d_in[0];
    const float* W = (const float*)d_in[1];
    float* out = (float*)d_out;
    float*  avgp   = (float*)d_ws;
    double* commit = (double*)((char*)d_ws + WS_COMMIT_OFF);
    float*  wkp    = (float*)((char*)d_ws + WS_WK_OFF);
    float*  WT2    = (float*)((char*)d_ws + WS_WT_OFF);
    float*  SrowG  = (float*)((char*)d_ws + WS_SROW_OFF);
    float*  resT   = out;                          // scratch: quantized region,
                                                   // overwritten last by gather
    const float* codesF = out + CODE_OFF;

    hipLaunchKernelGGL(init_acc, dim3(1), dim3(256), 0, stream, avgp, commit);
    hipLaunchKernelGGL(wnorm_kernel, dim3(768), dim3(256), 0, stream, W, wkp);
    hipLaunchKernelGGL(transpose_w, dim3(16, 4, 3), dim3(256), 0, stream, W, WT2);
    for (int l = 0; l < NLEV; ++l) {
        hipLaunchKernelGGL(stage_level, dim3(NROWS / 64), dim3(256), 0, stream,
                           x, W, codesF, resT, SrowG, l);
        hipLaunchKernelGGL(rvq_level, dim3(NROWS / 16), dim3(256), 0, stream,
                           resT, SrowG, WT2, wkp, out, avgp, commit, l);
    }
    hipLaunchKernelGGL(finalize_kernel, dim3(1), dim3(256), 0, stream, avgp, commit, out);
    hipLaunchKernelGGL(gather_kernel, dim3((NROWS * 32) / 256), dim3(256), 0, stream, W, out);
}

// Round 7
// 2402.231 us; speedup vs baseline: 1.3056x; 1.3056x over previous
//
#include <hip/hip_runtime.h>

// ResidualVectorQuantizer: N=131072, DIM=128, LEVELS=3, K=1024, BETA=0.25, USAGE_REG=1e-3
// Outputs (flat fp32 in d_out): quantized [N*128] | codes [N*3] | commit | usage
//
// Numerics contract with the np fp32 reference (validated previously — do not change):
//  - m = x·W_k: strict sequential fmaf chain over k=0..127, single accumulator.
//  - d = (S - 2*m) + w via __fsub_rn/__fmul_rn/__fadd_rn (no contraction).
//  - argmin: first occurrence on ties (lexicographic (value, index) min).
//  - residual chain (x - q0) - q1 elementwise fp32, recomputed from codes per level.
//  - Srow: per-8-elem left-assoc square sums, then 16-chunk ascending sum.
//  - losses: tolerance loose (~2%); commit = sum of d at argmin; avgp fp32; KL f64.
//
// Round 12. Six structurally different register-level variants all sit at
// 955-1045 us/level while VALUBusy/occupancy swing 16-47%/18-47%: the shared
// property is consuming operands from load-return registers, so the compiler
// drains vmcnt/lgkm inside every FMA burst and the allocator dismantles any
// hoisted pipeline (r6: VGPR=40 with a 32-reg acc!). Escape = the m97 tiled
// structure: W tiles double-buffered in LDS with ONE drain per tile, hidden
// behind 512 FMA cycles (issue loads early / ds_write late, T14); ds_read->FMA
// gets fine-grained lgkmcnt which the compiler handles well. With ~46 KB LDS
// the occupancy limit is LDS (3 blocks = 24 waves/CU), NOT VGPRs -> the
// allocator has no 8-wave target to chase: the register war is disarmed.
// Geometry: 512 threads, 16 rows x 1024 codes/block, 2 codes/thread (acc=32),
// KT=4 k-rows/tile. fmaf chain per (row,code) still k=0..127 single-acc.
// Checks: LDS ~46KB, Occupancy ~70%, WRITE ~133MB (no spill), dur 280-450/level.

#define NROWS   131072
#define DIMS    128
#define KCODES  1024
#define NLEV    3

#define QF_OFF   ((size_t)NROWS * DIMS)          // 16777216
#define CODE_OFF QF_OFF
#define SCAL_OFF (QF_OFF + (size_t)NROWS * 3)    // 17170432

// ---------------- ws layout ----------------
// avgp   : 3*1024 floats  @ 0        (12288 B)
// commit : 3 doubles      @ 12288    (24 B)
// wk     : 3*1024 floats  @ 12320    (12288 B)
// WT     : 3*128*1024 fl  @ 24608    (1572864 B)  k-major codebooks WT[l][k][c]
#define WS_COMMIT_OFF 12288
#define WS_WK_OFF     12320
#define WS_WT_OFF     24608

__global__ __launch_bounds__(256) void init_acc(float* avgp, double* commit) {
    for (int i = threadIdx.x; i < 3072; i += 256) avgp[i] = 0.0f;
    if (threadIdx.x < 3) commit[threadIdx.x] = 0.0;
}

__global__ __launch_bounds__(256) void wnorm_kernel(const float* __restrict__ W,
                                                    float* __restrict__ wk) {
    const int wave = threadIdx.x >> 6, lane = threadIdx.x & 63;
    const int c = blockIdx.x * 4 + wave;          // 0..3071 (level*1024 + k)
    const float2 v = *(const float2*)(W + (size_t)c * DIMS + 2 * lane);
    float s = v.x * v.x + v.y * v.y;
#pragma unroll
    for (int m = 32; m >= 1; m >>= 1) s += __shfl_xor(s, m, 64);
    if (lane == 0) wk[c] = s;
}

// WT[l][k][c] = W[l][c][k]   (plain k-major)
__global__ __launch_bounds__(256) void transpose_w(const float* __restrict__ W,
                                                   float* __restrict__ WT) {
    __shared__ float tile[32][65];
    const int l = blockIdx.z, k0 = blockIdx.y * 32, c0 = blockIdx.x * 64;
    const float* Wl = W + (size_t)l * KCODES * DIMS;
    float* WTl = WT + (size_t)l * DIMS * KCODES;
    {
        const int ci = threadIdx.x >> 2;            // 0..63
        const int kg = (threadIdx.x & 3) * 8;       // 0,8,16,24
        const float4 a = *(const float4*)(Wl + (size_t)(c0 + ci) * DIMS + k0 + kg);
        const float4 b = *(const float4*)(Wl + (size_t)(c0 + ci) * DIMS + k0 + kg + 4);
        tile[kg + 0][ci] = a.x; tile[kg + 1][ci] = a.y;
        tile[kg + 2][ci] = a.z; tile[kg + 3][ci] = a.w;
        tile[kg + 4][ci] = b.x; tile[kg + 5][ci] = b.y;
        tile[kg + 6][ci] = b.z; tile[kg + 7][ci] = b.w;
    }
    __syncthreads();
    {
        const int k = threadIdx.x >> 3;             // 0..31
        const int cg = (threadIdx.x & 7) * 8;       // 0..56
        float4 o0, o1;
        o0.x = tile[k][cg + 0]; o0.y = tile[k][cg + 1];
        o0.z = tile[k][cg + 2]; o0.w = tile[k][cg + 3];
        o1.x = tile[k][cg + 4]; o1.y = tile[k][cg + 5];
        o1.z = tile[k][cg + 6]; o1.w = tile[k][cg + 7];
        *(float4*)(WTl + (size_t)(k0 + k) * KCODES + c0 + cg)     = o0;
        *(float4*)(WTl + (size_t)(k0 + k) * KCODES + c0 + cg + 4) = o1;
    }
}

__global__ __launch_bounds__(512) void rvq_level(
    const float* __restrict__ x, const float* __restrict__ W,
    const float* __restrict__ WT, const float* __restrict__ wk,
    float* __restrict__ out, float* __restrict__ avgp,
    double* __restrict__ commit, const int level) {

    __shared__ float Wtile[2][4096];   // double-buffered W tile: 4 k-rows x 1024
    __shared__ float rowT[128][20];    // residual rows, k-major (pad 20: 16B-aligned, bank-spread)
    __shared__ float redf[16][17];
    __shared__ float Srow[16];
    __shared__ float wminv[16][8];     // per-wave argmin partials (8 waves)
    __shared__ int   wmini[16][8];
    __shared__ float rowmin[16];
    __shared__ float wsum[16][8];
    __shared__ float rcpL[16];

    const int t = threadIdx.x;
    const int wave = t >> 6, lane = t & 63;
    const int c = wave * 128 + lane * 2;          // this thread's 2 codes
    const size_t base = (size_t)blockIdx.x * 16;
    const float* codesF = out + CODE_OFF;
    const float* WTl = WT + (size_t)level * DIMS * KCODES;
    const float* wkl = wk + level * KCODES;

    // ---- phase 0 (t<256): stage 16 residual rows, k-major, bit-exact chain ----
    if (t < 256) {
        const int r = t >> 4, i = t & 15;
        const size_t n = base + r;
        float4 v0 = *(const float4*)(x + n * DIMS + i * 8);
        float4 v1 = *(const float4*)(x + n * DIMS + i * 8 + 4);
        for (int j = 0; j < level; ++j) {
            const int idx = (int)codesF[n * 3 + j];
            const float* q = W + ((size_t)(j * KCODES + idx)) * DIMS + i * 8;
            const float4 q0 = *(const float4*)q;
            const float4 q1 = *(const float4*)(q + 4);
            v0.x = __fsub_rn(v0.x, q0.x); v0.y = __fsub_rn(v0.y, q0.y);
            v0.z = __fsub_rn(v0.z, q0.z); v0.w = __fsub_rn(v0.w, q0.w);
            v1.x = __fsub_rn(v1.x, q1.x); v1.y = __fsub_rn(v1.y, q1.y);
            v1.z = __fsub_rn(v1.z, q1.z); v1.w = __fsub_rn(v1.w, q1.w);
        }
        rowT[i * 8 + 0][r] = v0.x; rowT[i * 8 + 1][r] = v0.y;
        rowT[i * 8 + 2][r] = v0.z; rowT[i * 8 + 3][r] = v0.w;
        rowT[i * 8 + 4][r] = v1.x; rowT[i * 8 + 5][r] = v1.y;
        rowT[i * 8 + 6][r] = v1.z; rowT[i * 8 + 7][r] = v1.w;
        float sq = v0.x * v0.x + v0.y * v0.y + v0.z * v0.z + v0.w * v0.w
                 + v1.x * v1.x + v1.y * v1.y + v1.z * v1.z + v1.w * v1.w;
        redf[r][i] = sq;
    }
    __syncthreads();
    if (t < 16) {
        float s = 0.f;
        for (int i = 0; i < 16; ++i) s += redf[t][i];
        Srow[t] = s;   // on-grid shift: order can't affect argmin/softmax
    }

    // ---- phase 1: tiled GEMM. acc[r] = row_r · W_{c,c+1}, k ascending. ----
    float2 acc[16];
#pragma unroll
    for (int r = 0; r < 16; ++r) { acc[r].x = 0.f; acc[r].y = 0.f; }

    // prologue: stage tile 0 (k-rows 0..3) into buf 0 via registers
    {
        const float4 g0 = *(const float4*)(WTl + (size_t)t * 4);
        const float4 g1 = *(const float4*)(WTl + 2048 + (size_t)t * 4);
        *(float4*)&Wtile[0][t * 4]        = g0;
        *(float4*)&Wtile[0][2048 + t * 4] = g1;
    }
    __syncthreads();   // covers Srow + tile 0

    int buf = 0;
#pragma unroll 1
    for (int kt = 0; kt < 32; ++kt) {
        // issue-early: global loads for tile kt+1 (clamped; dead on last iter)
        const float* Wn = WTl + (size_t)((kt + 1 < 32) ? (kt + 1) : 0) * 4096;
        const float4 g0 = *(const float4*)(Wn + (size_t)t * 4);
        const float4 g1 = *(const float4*)(Wn + 2048 + (size_t)t * 4);

        // consume current tile from LDS: 4 k-steps x 16 rows x 2 codes
        const float* Wt = &Wtile[buf][0];
#pragma unroll
        for (int kl = 0; kl < 4; ++kl) {
            const int k = kt * 4 + kl;
            const float2 wv = *(const float2*)&Wt[kl * 1024 + c];
#pragma unroll
            for (int rr = 0; rr < 4; ++rr) {
                const float4 rv = *(const float4*)&rowT[k][rr * 4];  // broadcast
                acc[rr * 4 + 0].x = fmaf(rv.x, wv.x, acc[rr * 4 + 0].x);
                acc[rr * 4 + 0].y = fmaf(rv.x, wv.y, acc[rr * 4 + 0].y);
                acc[rr * 4 + 1].x = fmaf(rv.y, wv.x, acc[rr * 4 + 1].x);
                acc[rr * 4 + 1].y = fmaf(rv.y, wv.y, acc[rr * 4 + 1].y);
                acc[rr * 4 + 2].x = fmaf(rv.z, wv.x, acc[rr * 4 + 2].x);
                acc[rr * 4 + 2].y = fmaf(rv.z, wv.y, acc[rr * 4 + 2].y);
                acc[rr * 4 + 3].x = fmaf(rv.w, wv.x, acc[rr * 4 + 3].x);
                acc[rr * 4 + 3].y = fmaf(rv.w, wv.y, acc[rr * 4 + 3].y);
            }
        }

        // write-late: vmcnt wait lands here, AFTER the 512-cycle FMA block (T14)
        *(float4*)&Wtile[buf ^ 1][t * 4]        = g0;
        *(float4*)&Wtile[buf ^ 1][2048 + t * 4] = g1;
        __syncthreads();
        buf ^= 1;
    }

    // ---- phase 2: d in place, per-row argmin (lexicographic shuffle reduce) ----
    const float2 wkv = *(const float2*)(wkl + c);
#pragma unroll
    for (int r = 0; r < 16; ++r) {
        const float Sr = Srow[r];
        float dx = __fadd_rn(__fsub_rn(Sr, __fmul_rn(2.0f, acc[r].x)), wkv.x);
        float dy = __fadd_rn(__fsub_rn(Sr, __fmul_rn(2.0f, acc[r].y)), wkv.y);
        acc[r].x = dx; acc[r].y = dy;
        float v = dx; int bi = c;
        if (dy < v) { v = dy; bi = c + 1; }
#pragma unroll
        for (int m = 1; m < 64; m <<= 1) {
            const float vo = __shfl_xor(v, m, 64);
            const int   io = __shfl_xor(bi, m, 64);
            if (vo < v || (vo == v && io < bi)) { v = vo; bi = io; }
        }
        if (lane == 0) { wminv[r][wave] = v; wmini[r][wave] = bi; }
    }
    __syncthreads();
    if (t < 16) {
        float v = wminv[t][0]; int bi = wmini[t][0];
        for (int w = 1; w < 8; ++w) {   // waves ascending == code ranges ascending
            const float vo = wminv[t][w]; const int io = wmini[t][w];
            if (vo < v || (vo == v && io < bi)) { v = vo; bi = io; }
        }
        rowmin[t] = v;
        out[CODE_OFF + (base + t) * 3 + level] = (float)bi;
    }
    __syncthreads();

    // ---- phase 3: e = exp(dmin - d) in place, row sums via shuffle ----
#pragma unroll
    for (int r = 0; r < 16; ++r) {
        const float mn = rowmin[r];
        const float ex = expf(__fsub_rn(mn, acc[r].x));
        const float ey = expf(__fsub_rn(mn, acc[r].y));
        acc[r].x = ex; acc[r].y = ey;
        float s = ex + ey;
#pragma unroll
        for (int m = 1; m < 64; m <<= 1) s += __shfl_xor(s, m, 64);
        if (lane == 0) wsum[r][wave] = s;
    }
    __syncthreads();
    if (t < 16) {
        float L = 0.f;
        for (int w = 0; w < 8; ++w) L += wsum[t][w];
        rcpL[t] = 1.0f / L;
    }
    if (t == 64) {   // commit partial: d at argmin == ||r - q||^2 (loss tolerance loose)
        double cs = 0.0;
        for (int r = 0; r < 16; ++r) cs += (double)rowmin[r];
        atomicAdd(&commit[level], cs);
    }
    __syncthreads();

    // ---- phase 4: avg_probs partials (fp32 atomics, one per code per block) ----
    {
        float s0 = 0.f, s1 = 0.f;
#pragma unroll
        for (int r = 0; r < 16; ++r) {
            const float rl = rcpL[r];
            s0 = fmaf(acc[r].x, rl, s0);
            s1 = fmaf(acc[r].y, rl, s1);
        }
        atomicAdd(&avgp[level * KCODES + c + 0], s0);
        atomicAdd(&avgp[level * KCODES + c + 1], s1);
    }
}

__global__ __launch_bounds__(256) void finalize_kernel(const float* __restrict__ avgp,
                                                       const double* __restrict__ commit,
                                                       float* __restrict__ out) {
    __shared__ double red[256];
    __shared__ float  kls[3];
    const int t = threadIdx.x;
    for (int l = 0; l < 3; ++l) {
        double p = 0.0;
        for (int k = t; k < KCODES; k += 256) {
            const float avg = avgp[l * KCODES + k] * (1.0f / 131072.0f);
            p += (double)avg * log((double)avg * 1024.0 + 1e-8);
        }
        red[t] = p; __syncthreads();
        for (int off = 128; off >= 1; off >>= 1) {
            if (t < off) red[t] += red[t + off];
            __syncthreads();
        }
        if (t == 0) kls[l] = (float)red[0];
        __syncthreads();
    }
    if (t == 0) {
        float cv = 0.f, u = 0.f;
        for (int l = 0; l < 3; ++l) {
            const float m = (float)(commit[l] * (1.0 / 16777216.0));
            cv = __fadd_rn(cv, m);                      // + mean((sg(r)-q)^2)
            cv = __fadd_rn(cv, __fmul_rn(0.25f, m));    // + BETA * mean((r-sg(q))^2)
            u = __fadd_rn(u, __fmul_rn(1e-3f, kls[l]));
        }
        out[SCAL_OFF]     = cv;
        out[SCAL_OFF + 1] = u;
    }
}

__global__ __launch_bounds__(256) void gather_kernel(const float* __restrict__ W,
                                                     float* __restrict__ out) {
    const size_t g = (size_t)blockIdx.x * 256 + threadIdx.x;   // f4 index
    const size_t n = g >> 5;
    const int f = (int)(g & 31);
    const float* codes = out + CODE_OFF + n * 3;
    const int c0 = (int)codes[0], c1 = (int)codes[1], c2 = (int)codes[2];
    const float4 a = *(const float4*)(W + (size_t)c0 * DIMS + 4 * f);
    const float4 b = *(const float4*)(W + (size_t)(KCODES + c1) * DIMS + 4 * f);
    const float4 c = *(const float4*)(W + (size_t)(2 * KCODES + c2) * DIMS + 4 * f);
    float4 o;   // ((q1 + q2) + q3), fp32 like reference
    o.x = __fadd_rn(__fadd_rn(a.x, b.x), c.x);
    o.y = __fadd_rn(__fadd_rn(a.y, b.y), c.y);
    o.z = __fadd_rn(__fadd_rn(a.z, b.z), c.z);
    o.w = __fadd_rn(__fadd_rn(a.w, b.w), c.w);
    *(float4*)(out + n * DIMS + 4 * f) = o;
}

extern "C" void kernel_launch(void* const* d_in, const int* in_sizes, int n_in,
                              void* d_out, int out_size, void* d_ws, size_t ws_size,
                              hipStream_t stream) {
    const float* x = (const float*)d_in[0];
    const float* W = (const float*)d_in[1];
    float* out = (float*)d_out;
    float*  avgp   = (float*)d_ws;
    double* commit = (double*)((char*)d_ws + WS_COMMIT_OFF);
    float*  wkp    = (float*)((char*)d_ws + WS_WK_OFF);
    float*  WT     = (float*)((char*)d_ws + WS_WT_OFF);

    hipLaunchKernelGGL(init_acc, dim3(1), dim3(256), 0, stream, avgp, commit);
    hipLaunchKernelGGL(wnorm_kernel, dim3(768), dim3(256), 0, stream, W, wkp);
    hipLaunchKernelGGL(transpose_w, dim3(16, 4, 3), dim3(256), 0, stream, W, WT);
    for (int l = 0; l < NLEV; ++l)
        hipLaunchKernelGGL(rvq_level, dim3(NROWS / 16), dim3(512), 0, stream,
                           x, W, WT, wkp, out, avgp, commit, l);
    hipLaunchKernelGGL(finalize_kernel, dim3(1), dim3(256), 0, stream, avgp, commit, out);
    hipLaunchKernelGGL(gather_kernel, dim3((NROWS * 32) / 256), dim3(256), 0, stream, W, out);
}